// Round 6
// baseline (244.847 us; speedup 1.0000x reference)
//
#include <hip/hip_runtime.h>
#include <hip/hip_cooperative_groups.h>

namespace cg = cooperative_groups;

#define N_NODES 3072
#define N_EDGES 3072
#define N_LG    6144
#define F       64
#define H       4
#define HASH_SZ 16384
#define HASH_MASK (HASH_SZ - 1)

// workspace layout (float offsets)
#define OFF_PV   0                                  // 2 kinds * N*256 = 1572864 (flat [M,256] per kind)
#define OFF_SRK  (OFF_PV + 2*H*N_NODES*F)           // 2*H*F = 512
#define OFF_ATT  (OFF_SRK + 2*H*F)                  // 2 kinds * H*N = 24576
#define OFF_HASH (OFF_ATT + 2*H*N_NODES)            // 4*HASH_SZ ints: keys_g, keys_lg, vals_g, vals_lg

#define NBLK 256

__device__ __forceinline__ unsigned hash_slot(unsigned key) {
    return (key * 2654435761u >> 16) & HASH_MASK;
}

__device__ __forceinline__ int hash_is_winner(
    unsigned key, const unsigned* __restrict__ keys, const int* __restrict__ vals, int e)
{
    unsigned idx = hash_slot(key);
    while (keys[idx] != key) idx = (idx + 1) & HASH_MASK;
    return vals[idx] == e;
}

// LDS float offsets within the shared pool
#define L_SIN   0        // 64*68 = 4352 (srk); proj_v uses first 32*68=2176
#define L_KL    4352     // 256
#define L_WK    4608     // 256
#define L_BK    4864     // 4
#define L_RED   4868     // 16
#define LDS_FLOATS (L_RED + 16)

__global__ __launch_bounds__(256) void mega_kernel(
    const float* __restrict__ node_in, const float* __restrict__ edge_in,
    const int* __restrict__ src, const int* __restrict__ dst,
    const int* __restrict__ lg_src, const int* __restrict__ lg_dst,
    const float* __restrict__ nqW, const float* __restrict__ nqb,
    const float* __restrict__ nkW, const float* __restrict__ nkb,
    const float* __restrict__ nvW, const float* __restrict__ nvb,
    const float* __restrict__ eqW, const float* __restrict__ eqb,
    const float* __restrict__ ekW, const float* __restrict__ ekb,
    const float* __restrict__ evW, const float* __restrict__ evb,
    float* __restrict__ ws, float* __restrict__ out)
{
    cg::grid_group grid = cg::this_grid();
    const int b = blockIdx.x, t = threadIdx.x;
    const int gtid = b * 256 + t;
    __shared__ float lds[LDS_FLOATS];

    unsigned* keys_g  = (unsigned*)(ws + OFF_HASH);
    unsigned* keys_lg = keys_g + HASH_SZ;
    int* vals_g  = (int*)(keys_g + 2 * HASH_SZ);
    int* vals_lg = vals_g + HASH_SZ;

    // ---------------- phase 0: init (out zero, hash init, srk zero) ----------------
    {
        float4* out4 = (float4*)out;                 // 98304 float4
        if (gtid < 98304) out4[gtid] = make_float4(0.f, 0.f, 0.f, 0.f);
        const int i2 = gtid + 65536;
        if (i2 < 98304) out4[i2] = make_float4(0.f, 0.f, 0.f, 0.f);
        int4* hash4 = (int4*)(ws + OFF_HASH);        // 16384 int4: first 8192 keys -> -1, rest vals -> 0
        if (gtid < 16384) hash4[gtid] = (gtid < 8192) ? make_int4(-1, -1, -1, -1) : make_int4(0, 0, 0, 0);
        if (gtid < 512) ws[OFF_SRK + gtid] = 0.f;
    }
    grid.sync();

    // ---------------- phase 1: srk (0..95) | proj_v (96..255) | hash insert (220..255) ----------------
    if (b < 96) {
        // fused K-projection + srk partial reduction (reshape-flat semantics, verified R5)
        const int tile = b % 48, kind = b / 48;
        const int h = tile / 12, m0 = (tile % 12) * 256, r0 = tile * 64;
        const float* in = kind ? edge_in : node_in;
        const float* Wk = kind ? ekW : nkW;
        const float* bk = kind ? ekb : nkb;
        float* sin_ = lds + L_SIN;
        float* k_lds = lds + L_KL;
        float* wk_s = lds + L_WK;
        float* bk_s = lds + L_BK;
        #pragma unroll
        for (int i = 0; i < 4; ++i) {        // stage 64 rows x 16 float4, padded stride 68
            const int idx = t + i * 256;
            const int m = idx >> 4, q = idx & 15;
            float4 v = ((const float4*)(in + (size_t)(r0 + m) * F))[q];
            *(float4*)&sin_[m * 68 + q * 4] = v;
        }
        wk_s[t] = Wk[t];
        if (t < 4) bk_s[t] = bk[t];
        __syncthreads();
        {   // k value for local g = t -> row rl = t>>2, col c = t&3
            const int rl = t >> 2, c = t & 3;
            float acc = bk_s[c];
            #pragma unroll
            for (int j = 0; j < F; ++j) acc += sin_[rl * 68 + j] * wk_s[j * 4 + c];
            k_lds[t] = acc;
        }
        __syncthreads();
        {   // partial srk over this block's m-range (coalesced global reads)
            const int c = t >> 6, f = t & 63;
            float acc = 0.f;
            const float* base = in + (size_t)(m0 + c * 64) * F + f;
            #pragma unroll
            for (int mp = 0; mp < 64; ++mp) acc += base[(size_t)mp * F] * k_lds[c * 64 + mp];
            atomicAdd(&ws[OFF_SRK + (kind * H + h) * F + f], acc);
        }
    } else {
        // proj_v: task p = b-96; blocks 96..127 also take p+160
        float* sin_ = lds + L_SIN;
        const int ntask = (b < 128) ? 2 : 1;
        for (int it = 0; it < ntask; ++it) {
            const int p = (it == 0) ? (b - 96) : (b - 96 + 160);
            const int kind = p / 96, m0 = (p % 96) * 32;
            const float* in = kind ? edge_in : node_in;
            const float* W  = kind ? evW : nvW;
            const float* bv = kind ? evb : nvb;
            if (it) __syncthreads();             // drain reads of sin_ from previous task
            #pragma unroll
            for (int i = 0; i < 2; ++i) {        // stage 32 rows x 16 float4
                const int idx = t + i * 256;
                const int m = idx >> 4, q = idx & 15;
                float4 v = ((const float4*)(in + (size_t)(m0 + m) * F))[q];
                *(float4*)&sin_[m * 68 + q * 4] = v;
            }
            __syncthreads();
            float acc[32];
            const float b0 = bv[t];
            #pragma unroll
            for (int r = 0; r < 32; ++r) acc[r] = b0;
            #pragma unroll
            for (int k4 = 0; k4 < 16; ++k4) {
                const float w0 = W[(k4 * 4 + 0) * 256 + t];
                const float w1 = W[(k4 * 4 + 1) * 256 + t];
                const float w2 = W[(k4 * 4 + 2) * 256 + t];
                const float w3 = W[(k4 * 4 + 3) * 256 + t];
                #pragma unroll
                for (int r = 0; r < 32; ++r) {
                    float4 v = *(const float4*)&sin_[r * 68 + k4 * 4];
                    acc[r] = fmaf(v.x, w0, fmaf(v.y, w1, fmaf(v.z, w2, fmaf(v.w, w3, acc[r]))));
                }
            }
            float* V = ws + OFF_PV + (size_t)kind * H * N_NODES * F;
            #pragma unroll
            for (int r = 0; r < 32; ++r)
                V[(size_t)(m0 + r) * 256 + t] = acc[r];   // FLAT [M,256]
        }
        // hash insert on blocks 220..255 (36 blocks x 256 threads = 9216 entries)
        if (b >= 220) {
            int q = b - 220;
            const int* s; const int* d; unsigned* keys; int* vals; int n; int e0;
            if (q < 12) { s = src;    d = dst;    keys = keys_g;  vals = vals_g;  n = N_EDGES; e0 = q * 256; }
            else { s = lg_src; d = lg_dst; keys = keys_lg; vals = vals_lg; n = N_LG; e0 = (q - 12) * 256; }
            const int e = e0 + t;
            if (e < n) {
                const unsigned key = (unsigned)(s[e] * N_NODES + d[e]);
                unsigned idx = hash_slot(key);
                while (true) {
                    unsigned prev = atomicCAS(&keys[idx], 0xFFFFFFFFu, key);
                    if (prev == 0xFFFFFFFFu || prev == key) { atomicMax(&vals[idx], e); break; }
                    idx = (idx + 1) & HASH_MASK;
                }
            }
        }
    }
    grid.sync();

    // ---------------- phase 2: att (blocks 0..7), 256 threads, 12 rows/thread ----------------
    if (b < 8) {
        const int h = b & 3, kind = b >> 2;
        const float* in = kind ? edge_in : node_in;
        const float* Wq = kind ? eqW : nqW;
        const float* bq = kind ? eqb : nqb;
        float* att = ws + OFF_ATT + (kind * H + h) * N_NODES;
        float* s_srk = lds + L_SIN;        // 64
        float* s_w   = lds + L_SIN + 64;   // 256  [c4][j]
        float* s_beff = lds + L_SIN + 320; // 4
        float* sred  = lds + L_RED;        // 8 used
        if (t < 64) s_srk[t] = ws[OFF_SRK + (kind * H + h) * F + t];
        __syncthreads();
        {
            const int c4 = t >> 6, j = t & 63;
            float we = 0.f;
            #pragma unroll
            for (int f = 0; f < F; ++f) we += Wq[j * 256 + c4 * 64 + f] * s_srk[f];
            s_w[c4 * 64 + j] = we;
        }
        if (t < 4) {
            float be = 0.f;
            #pragma unroll
            for (int f = 0; f < F; ++f) be += bq[t * 64 + f] * s_srk[f];
            s_beff[t] = be;
        }
        __syncthreads();
        float x[12];
        float mx = -1e30f;
        #pragma unroll
        for (int j = 0; j < 12; ++j) {
            const int m = t + 256 * j;
            const int row = h * 768 + (m >> 2);
            const int c4 = m & 3;
            const float4* q4 = (const float4*)(in + (size_t)row * F);
            const float* w = s_w + c4 * 64;
            float a = 0.f;
            #pragma unroll
            for (int i = 0; i < 16; ++i) {
                float4 v = q4[i];
                a += v.x * w[i * 4] + v.y * w[i * 4 + 1] + v.z * w[i * 4 + 2] + v.w * w[i * 4 + 3];
            }
            x[j] = (a + s_beff[c4]) * 0.125f;
            mx = fmaxf(mx, x[j]);
        }
        const int wid = t >> 6, lane = t & 63;
        #pragma unroll
        for (int o = 1; o < 64; o <<= 1) mx = fmaxf(mx, __shfl_xor(mx, o));
        if (lane == 0) sred[wid] = mx;
        __syncthreads();
        mx = fmaxf(fmaxf(sred[0], sred[1]), fmaxf(sred[2], sred[3]));
        float s = 0.f;
        #pragma unroll
        for (int j = 0; j < 12; ++j) { x[j] = __expf(x[j] - mx); s += x[j]; }
        #pragma unroll
        for (int o = 1; o < 64; o <<= 1) s += __shfl_xor(s, o);
        if (lane == 0) sred[4 + wid] = s;
        __syncthreads();
        const float inv = 1.0f / (sred[4] + sred[5] + sred[6] + sred[7]);
        #pragma unroll
        for (int j = 0; j < 12; ++j) att[t + 256 * j] = x[j] * inv;
    }
    grid.sync();

    // ---------------- phase 3: scatter (9216 tasks, 64 threads each, 4/block/sweep) ----------------
    {
        const int g = t >> 6, f = t & 63;
        for (int task = b * 4 + g; task < N_EDGES + N_LG; task += NBLK * 4) {
            if (task < N_EDGES) {
                const int e = task;
                const int s = src[e], d = dst[e];
                const unsigned key = (unsigned)(s * N_NODES + d);
                if (!hash_is_winner(key, keys_g, vals_g, e)) continue;
                const float* att = ws + OFF_ATT + H * N_NODES;          // edge attention (kind=1)
                const float* V   = ws + OFF_PV;                          // node V (kind=0), flat
                float acc = 0.f;
                #pragma unroll
                for (int h = 0; h < H; ++h)
                    acc += att[h * N_EDGES + e] * V[(size_t)h * N_NODES * F + (size_t)d * F + f];
                atomicAdd(&out[s * F + f], 0.25f * acc);
            } else {
                const int l = task - N_EDGES;
                const int e1 = lg_src[l], e2 = lg_dst[l];
                const unsigned key = (unsigned)(e1 * N_NODES + e2);
                if (!hash_is_winner(key, keys_lg, vals_lg, l)) continue;
                const int conn = dst[e1];
                const float* att = ws + OFF_ATT;                          // node attention (kind=0)
                const float* V   = ws + OFF_PV + (size_t)H * N_EDGES * F; // edge V (kind=1), flat
                float acc = 0.f;
                #pragma unroll
                for (int h = 0; h < H; ++h)
                    acc += att[h * N_NODES + conn] * V[(size_t)h * N_EDGES * F + (size_t)e2 * F + f];
                atomicAdd(&out[N_NODES * F + e1 * F + f], 0.25f * acc);
            }
        }
    }
}

extern "C" void kernel_launch(void* const* d_in, const int* in_sizes, int n_in,
                              void* d_out, int out_size, void* d_ws, size_t ws_size,
                              hipStream_t stream)
{
    const float* node_in = (const float*)d_in[0];
    const float* edge_in = (const float*)d_in[1];
    const int* src    = (const int*)d_in[2];
    const int* dst    = (const int*)d_in[3];
    const int* lg_src = (const int*)d_in[4];
    const int* lg_dst = (const int*)d_in[5];
    const float* nqW = (const float*)d_in[6];  const float* nqb = (const float*)d_in[7];
    const float* nkW = (const float*)d_in[8];  const float* nkb = (const float*)d_in[9];
    const float* nvW = (const float*)d_in[10]; const float* nvb = (const float*)d_in[11];
    const float* eqW = (const float*)d_in[12]; const float* eqb = (const float*)d_in[13];
    const float* ekW = (const float*)d_in[14]; const float* ekb = (const float*)d_in[15];
    const float* evW = (const float*)d_in[16]; const float* evb = (const float*)d_in[17];

    float* ws  = (float*)d_ws;
    float* out = (float*)d_out;

    void* args[] = {
        (void*)&node_in, (void*)&edge_in, (void*)&src, (void*)&dst,
        (void*)&lg_src, (void*)&lg_dst,
        (void*)&nqW, (void*)&nqb, (void*)&nkW, (void*)&nkb, (void*)&nvW, (void*)&nvb,
        (void*)&eqW, (void*)&eqb, (void*)&ekW, (void*)&ekb, (void*)&evW, (void*)&evb,
        (void*)&ws, (void*)&out
    };
    hipLaunchCooperativeKernel((const void*)mega_kernel, dim3(NBLK), dim3(256),
                               args, 0, stream);
}

// Round 7
// 140.244 us; speedup vs baseline: 1.7459x; 1.7459x over previous
//
#include <hip/hip_runtime.h>

#define N_NODES 3072
#define N_EDGES 3072
#define N_LG    6144
#define F       64
#define H       4
#define HASH_SZ 16384
#define HASH_MASK (HASH_SZ - 1)

// workspace layout (float offsets)
#define OFF_PV   0                                  // 2 kinds * N*256 = 1572864 (flat [M,256] per kind)
#define OFF_SRK  (OFF_PV + 2*H*N_NODES*F)           // 2*H*F = 512
#define OFF_ATT  (OFF_SRK + 2*H*F)                  // 2 kinds * H*N = 24576
#define OFF_HASH (OFF_ATT + 2*H*N_NODES)            // 4*HASH_SZ ints: keys_g, keys_lg, vals_g, vals_lg

__device__ __forceinline__ unsigned hash_slot(unsigned key) {
    return (key * 2654435761u >> 16) & HASH_MASK;
}

__device__ __forceinline__ int hash_is_winner(
    unsigned key, const unsigned* __restrict__ keys, const int* __restrict__ vals, int e)
{
    unsigned idx = hash_slot(key);
    while (keys[idx] != key) idx = (idx + 1) & HASH_MASK;
    return vals[idx] == e;
}

// grid 449 blocks: 384 zero out (98304 float4), 64 hash init (16384 int4), 1 srk zero
__global__ __launch_bounds__(256) void init_kernel(
    float4* __restrict__ out, int4* __restrict__ hash, float* __restrict__ srk)
{
    const int b = blockIdx.x, t = threadIdx.x;
    if (b < 384) {
        out[b * 256 + t] = make_float4(0.f, 0.f, 0.f, 0.f);
    } else if (b < 448) {
        const int idx = (b - 384) * 256 + t;   // first 8192 int4 = keys -> -1, rest vals -> 0
        hash[idx] = (idx < 8192) ? make_int4(-1, -1, -1, -1) : make_int4(0, 0, 0, 0);
    } else {
        srk[t] = 0.f;
        srk[t + 256] = 0.f;
    }
}

// LDS float offsets within the shared pool (sized for the srk path, 19.5 KB)
#define L_SIN   0        // 64*68 = 4352 (srk); proj_v uses first 32*68=2176
#define L_KL    4352     // 256
#define L_WK    4608     // 256
#define L_BK    4864     // 4
#define LDS_FLOATS (L_BK + 4)

// phase1: 324 blocks x 256.
//   b <  96          : fused K-proj + srk partial reduction  (96 = 48 tiles x 2 kinds)
//   96 <= b < 288    : proj_v task p = b-96  (192 = 96 tiles x 2 kinds)
//   288 <= b < 324   : hash insert (36 blocks: 12 g + 24 lg)
__global__ __launch_bounds__(256) void phase1_kernel(
    const float* __restrict__ node_in, const float* __restrict__ edge_in,
    const int* __restrict__ src, const int* __restrict__ dst,
    const int* __restrict__ lg_src, const int* __restrict__ lg_dst,
    const float* __restrict__ nkW, const float* __restrict__ nkb,
    const float* __restrict__ ekW, const float* __restrict__ ekb,
    const float* __restrict__ nvW, const float* __restrict__ nvb,
    const float* __restrict__ evW, const float* __restrict__ evb,
    float* __restrict__ ws)
{
    const int b = blockIdx.x, t = threadIdx.x;
    __shared__ float lds[LDS_FLOATS];

    if (b < 96) {
        // ----- srk: k[h,m] = in[(h*3072+m)>>2,:]·Wk[:,(h*3072+m)&3] + bk[...] ; srk += in^T k
        const int tile = b % 48, kind = b / 48;
        const int h = tile / 12, m0 = (tile % 12) * 256, r0 = tile * 64;
        const float* in = kind ? edge_in : node_in;
        const float* Wk = kind ? ekW : nkW;
        const float* bk = kind ? ekb : nkb;
        float* sin_ = lds + L_SIN;
        float* k_lds = lds + L_KL;
        float* wk_s = lds + L_WK;
        float* bk_s = lds + L_BK;
        #pragma unroll
        for (int i = 0; i < 4; ++i) {        // stage 64 rows x 16 float4, padded stride 68
            const int idx = t + i * 256;
            const int m = idx >> 4, q = idx & 15;
            float4 v = ((const float4*)(in + (size_t)(r0 + m) * F))[q];
            *(float4*)&sin_[m * 68 + q * 4] = v;
        }
        wk_s[t] = Wk[t];
        if (t < 4) bk_s[t] = bk[t];
        __syncthreads();
        {   // k value for local g = t -> row rl = t>>2, col c = t&3
            const int rl = t >> 2, c = t & 3;
            float acc = bk_s[c];
            #pragma unroll
            for (int j = 0; j < F; ++j) acc += sin_[rl * 68 + j] * wk_s[j * 4 + c];
            k_lds[t] = acc;
        }
        __syncthreads();
        {   // partial srk over this block's m-range (coalesced global reads)
            const int c = t >> 6, f = t & 63;
            float acc = 0.f;
            const float* base = in + (size_t)(m0 + c * 64) * F + f;
            #pragma unroll
            for (int mp = 0; mp < 64; ++mp) acc += base[(size_t)mp * F] * k_lds[c * 64 + mp];
            atomicAdd(&ws[OFF_SRK + (kind * H + h) * F + f], acc);
        }
    } else if (b < 288) {
        // ----- proj_v: 32 rows/tile, thread = one of 256 cols, FLAT [M,256] store
        const int p = b - 96;
        const int kind = p / 96, m0 = (p % 96) * 32;
        const float* in = kind ? edge_in : node_in;
        const float* W  = kind ? evW : nvW;
        const float* bv = kind ? evb : nvb;
        float* sin_ = lds + L_SIN;
        #pragma unroll
        for (int i = 0; i < 2; ++i) {        // stage 32 rows x 16 float4
            const int idx = t + i * 256;
            const int m = idx >> 4, q = idx & 15;
            float4 v = ((const float4*)(in + (size_t)(m0 + m) * F))[q];
            *(float4*)&sin_[m * 68 + q * 4] = v;
        }
        __syncthreads();
        float acc[32];
        const float b0 = bv[t];
        #pragma unroll
        for (int r = 0; r < 32; ++r) acc[r] = b0;
        #pragma unroll
        for (int k4 = 0; k4 < 16; ++k4) {
            const float w0 = W[(k4 * 4 + 0) * 256 + t];
            const float w1 = W[(k4 * 4 + 1) * 256 + t];
            const float w2 = W[(k4 * 4 + 2) * 256 + t];
            const float w3 = W[(k4 * 4 + 3) * 256 + t];
            #pragma unroll
            for (int r = 0; r < 32; ++r) {
                float4 v = *(const float4*)&sin_[r * 68 + k4 * 4];
                acc[r] = fmaf(v.x, w0, fmaf(v.y, w1, fmaf(v.z, w2, fmaf(v.w, w3, acc[r]))));
            }
        }
        float* V = ws + OFF_PV + (size_t)kind * H * N_NODES * F;
        #pragma unroll
        for (int r = 0; r < 32; ++r)
            V[(size_t)(m0 + r) * 256 + t] = acc[r];   // FLAT [M,256]
    } else {
        // ----- hash insert (last-writer-wins = max edge idx per (s,d) key)
        unsigned* keys_g  = (unsigned*)(ws + OFF_HASH);
        unsigned* keys_lg = keys_g + HASH_SZ;
        int* vals_g  = (int*)(keys_g + 2 * HASH_SZ);
        int* vals_lg = vals_g + HASH_SZ;
        int q = b - 288;
        const int* s; const int* d; unsigned* keys; int* vals; int n; int e0;
        if (q < 12) { s = src;    d = dst;    keys = keys_g;  vals = vals_g;  n = N_EDGES; e0 = q * 256; }
        else { s = lg_src; d = lg_dst; keys = keys_lg; vals = vals_lg; n = N_LG; e0 = (q - 12) * 256; }
        const int e = e0 + t;
        if (e < n) {
            const unsigned key = (unsigned)(s[e] * N_NODES + d[e]);
            unsigned idx = hash_slot(key);
            while (true) {
                unsigned prev = atomicCAS(&keys[idx], 0xFFFFFFFFu, key);
                if (prev == 0xFFFFFFFFu || prev == key) { atomicMax(&vals[idx], e); break; }
                idx = (idx + 1) & HASH_MASK;
            }
        }
    }
}

// fused wq_eff + x + softmax (reshape-flat semantics).  grid (H,2); block 1024, 3 m/thread.
__global__ __launch_bounds__(1024) void att_kernel(
    const float* __restrict__ node_in, const float* __restrict__ edge_in,
    const float* __restrict__ nqW, const float* __restrict__ nqb,
    const float* __restrict__ eqW, const float* __restrict__ eqb,
    float* __restrict__ ws)
{
    const int h = blockIdx.x, kind = blockIdx.y, tid = threadIdx.x;
    const float* in = kind ? edge_in : node_in;
    const float* Wq = kind ? eqW : nqW;
    const float* bq = kind ? eqb : nqb;
    float* att = ws + OFF_ATT + (kind * H + h) * N_NODES;
    __shared__ float s_srk[F];
    __shared__ float s_w[256];     // [c4][j]
    __shared__ float s_beff[4];
    __shared__ float sred[16];
    if (tid < F) s_srk[tid] = ws[OFF_SRK + (kind * H + h) * F + tid];
    __syncthreads();
    if (tid < 256) {
        const int c4 = tid >> 6, j = tid & 63;
        float we = 0.f;
        #pragma unroll
        for (int f = 0; f < F; ++f) we += Wq[j * 256 + c4 * 64 + f] * s_srk[f];
        s_w[c4 * 64 + j] = we;
    } else if (tid < 260) {
        const int c4 = tid - 256;
        float be = 0.f;
        #pragma unroll
        for (int f = 0; f < F; ++f) be += bq[c4 * 64 + f] * s_srk[f];
        s_beff[c4] = be;
    }
    __syncthreads();
    float x[3];
    float mx = -1e30f;
    #pragma unroll
    for (int j = 0; j < 3; ++j) {
        const int m = tid * 3 + j;
        const int row = h * 768 + (m >> 2);
        const int c4 = m & 3;
        const float4* q4 = (const float4*)(in + (size_t)row * F);
        const float* w = s_w + c4 * 64;
        float a = 0.f;
        #pragma unroll
        for (int i = 0; i < 16; ++i) {
            float4 v = q4[i];
            a += v.x * w[i * 4] + v.y * w[i * 4 + 1] + v.z * w[i * 4 + 2] + v.w * w[i * 4 + 3];
        }
        x[j] = (a + s_beff[c4]) * 0.125f;
        mx = fmaxf(mx, x[j]);
    }
    #pragma unroll
    for (int o = 1; o < 64; o <<= 1) mx = fmaxf(mx, __shfl_xor(mx, o));
    const int wid = tid >> 6, lane = tid & 63;
    if (lane == 0) sred[wid] = mx;
    __syncthreads();
    if (tid == 0) { float m2 = sred[0]; for (int i = 1; i < 16; ++i) m2 = fmaxf(m2, sred[i]); sred[0] = m2; }
    __syncthreads();
    mx = sred[0];
    __syncthreads();
    float s = 0.f;
    #pragma unroll
    for (int j = 0; j < 3; ++j) { x[j] = __expf(x[j] - mx); s += x[j]; }
    #pragma unroll
    for (int o = 1; o < 64; o <<= 1) s += __shfl_xor(s, o);
    if (lane == 0) sred[wid] = s;
    __syncthreads();
    if (tid == 0) { float t = 0.f; for (int i = 0; i < 16; ++i) t += sred[i]; sred[0] = t; }
    __syncthreads();
    const float inv = 1.0f / sred[0];
    #pragma unroll
    for (int j = 0; j < 3; ++j) att[tid * 3 + j] = x[j] * inv;
}

// merged scatters.  grid 2304 x 256; 4 tasks/block (one 64-lane wave each).
// V read via reshape-flat indexing: v[h,m,f] = Vflat[h*196608 + m*64 + f]
__global__ __launch_bounds__(256) void scatter_kernel(
    const int* __restrict__ src, const int* __restrict__ dst,
    const int* __restrict__ lg_src, const int* __restrict__ lg_dst,
    const float* __restrict__ ws,
    float* __restrict__ out)
{
    const unsigned* keys_g  = (const unsigned*)(ws + OFF_HASH);
    const unsigned* keys_lg = keys_g + HASH_SZ;
    const int* vals_g  = (const int*)(keys_g + 2 * HASH_SZ);
    const int* vals_lg = vals_g + HASH_SZ;
    const int g = threadIdx.x >> 6, f = threadIdx.x & 63;
    const int task = blockIdx.x * 4 + g;
    if (task < N_EDGES) {
        const int e = task;
        const int s = src[e], d = dst[e];
        const unsigned key = (unsigned)(s * N_NODES + d);
        if (!hash_is_winner(key, keys_g, vals_g, e)) return;
        const float* att = ws + OFF_ATT + H * N_NODES;          // edge attention (kind=1)
        const float* V   = ws + OFF_PV;                          // node V (kind=0), flat
        float acc = 0.f;
        #pragma unroll
        for (int h = 0; h < H; ++h)
            acc += att[h * N_EDGES + e] * V[(size_t)h * N_NODES * F + (size_t)d * F + f];
        atomicAdd(&out[s * F + f], 0.25f * acc);
    } else {
        const int l = task - N_EDGES;
        const int e1 = lg_src[l], e2 = lg_dst[l];
        const unsigned key = (unsigned)(e1 * N_NODES + e2);
        if (!hash_is_winner(key, keys_lg, vals_lg, l)) return;
        const int conn = dst[e1];
        const float* att = ws + OFF_ATT;                          // node attention (kind=0)
        const float* V   = ws + OFF_PV + (size_t)H * N_EDGES * F; // edge V (kind=1), flat
        float acc = 0.f;
        #pragma unroll
        for (int h = 0; h < H; ++h)
            acc += att[h * N_NODES + conn] * V[(size_t)h * N_EDGES * F + (size_t)e2 * F + f];
        atomicAdd(&out[N_NODES * F + e1 * F + f], 0.25f * acc);
    }
}

extern "C" void kernel_launch(void* const* d_in, const int* in_sizes, int n_in,
                              void* d_out, int out_size, void* d_ws, size_t ws_size,
                              hipStream_t stream)
{
    const float* node_in = (const float*)d_in[0];
    const float* edge_in = (const float*)d_in[1];
    const int* src    = (const int*)d_in[2];
    const int* dst    = (const int*)d_in[3];
    const int* lg_src = (const int*)d_in[4];
    const int* lg_dst = (const int*)d_in[5];
    const float* nqW = (const float*)d_in[6];  const float* nqb = (const float*)d_in[7];
    const float* nkW = (const float*)d_in[8];  const float* nkb = (const float*)d_in[9];
    const float* nvW = (const float*)d_in[10]; const float* nvb = (const float*)d_in[11];
    const float* eqW = (const float*)d_in[12]; const float* eqb = (const float*)d_in[13];
    const float* ekW = (const float*)d_in[14]; const float* ekb = (const float*)d_in[15];
    const float* evW = (const float*)d_in[16]; const float* evb = (const float*)d_in[17];

    float* ws  = (float*)d_ws;
    float* out = (float*)d_out;

    hipLaunchKernelGGL(init_kernel, dim3(449), dim3(256), 0, stream,
                       (float4*)out, (int4*)(ws + OFF_HASH), ws + OFF_SRK);
    hipLaunchKernelGGL(phase1_kernel, dim3(324), dim3(256), 0, stream,
                       node_in, edge_in, src, dst, lg_src, lg_dst,
                       nkW, nkb, ekW, ekb, nvW, nvb, evW, evb, ws);
    hipLaunchKernelGGL(att_kernel, dim3(H, 2), dim3(1024), 0, stream,
                       node_in, edge_in, nqW, nqb, eqW, eqb, ws);
    hipLaunchKernelGGL(scatter_kernel, dim3((N_EDGES + N_LG) / 4), dim3(256), 0, stream,
                       src, dst, lg_src, lg_dst, ws, out);
}